// Round 17
// baseline (132.756 us; speedup 1.0000x reference)
//
#include <hip/hip_runtime.h>
#include <stdint.h>

// S=4096, D=64.  out = (t * floor(t*rr)/R) @ V,  t = (QK^T*8) * dropout_keep/0.9
// R17 = R16 (producer/consumer wave specialization: 4 compute waves with a
// 4-DMA/tile vmcnt ledger + 1 producer wave streaming/packing the 64MB
// u-stream 2 tiles ahead into a 2KB LDS nibble-mask dbuf) + THE FIX:
// consumer mask row index was missing the w*16 wave offset (all waves read
// wave 0's masks -> absmax 0.154). One line: um8[bu][(w*16+quad*4+rg)*16].

#define S 4096
#define D 64
#define NCHUNK 8              // grid = 64 i-blocks * 8 chunks = 512 blocks
#define JCHUNK (S / NCHUNK)   // 512
#define JT 64
#define NTILES (JCHUNK / JT)  // 8
#define LDP 72                // pb pitch in shorts
#define KSCALE (8.0f / 0.9f)

typedef float f32x4 __attribute__((ext_vector_type(4)));
typedef short s16x8 __attribute__((ext_vector_type(8)));
typedef unsigned short u16x4 __attribute__((ext_vector_type(4)));
typedef const __attribute__((address_space(1))) unsigned g_u32;
typedef __attribute__((address_space(3))) unsigned lds_u32;

#define CLOBBER() __asm__ volatile("" ::: "memory")

__device__ inline unsigned short f2bf(float f) {
    union { float f; unsigned u; } v; v.f = f;
    unsigned r = v.u + 0x7fffu + ((v.u >> 16) & 1u);
    return (unsigned short)(r >> 16);
}

// ---- prep: Q->bf16, K->bf16*KSCALE (blocks 0..511), V->V^T (512..575) ----
__global__ void prep_all(const float* __restrict__ Q,
                         const float* __restrict__ Kf,
                         const float* __restrict__ V,
                         short* __restrict__ Qbf, short* __restrict__ Kbf,
                         short* __restrict__ VTbf, int* __restrict__ sumr) {
    __shared__ short tile[64 * 68];
    const int b   = blockIdx.x;
    const int tid = threadIdx.x;
    if (b == 0 && tid == 0) *sumr = 0;

    if (b < 512) {
        const int idx = b * 256 + tid;               // 131072 float4 slots
        if (idx < 65536) {
            float4 v = ((const float4*)Q)[idx];
            u16x4 o; o[0] = f2bf(v.x); o[1] = f2bf(v.y); o[2] = f2bf(v.z); o[3] = f2bf(v.w);
            ((u16x4*)Qbf)[idx] = o;
        } else {
            const int k = idx - 65536;
            float4 v = ((const float4*)Kf)[k];
            u16x4 o; o[0] = f2bf(v.x * KSCALE); o[1] = f2bf(v.y * KSCALE);
                     o[2] = f2bf(v.z * KSCALE); o[3] = f2bf(v.w * KSCALE);
            ((u16x4*)Kbf)[k] = o;
        }
    } else {
        const int j0 = (b - 512) * 64;
#pragma unroll
        for (int it = 0; it < 4; ++it) {
            const int f4 = tid + it * 256;
            const int row = f4 >> 4, c4 = (f4 & 15) * 4;
            float4 v = *(const float4*)&V[(size_t)(j0 + row) * D + c4];
            tile[(c4 + 0) * 68 + row] = (short)f2bf(v.x);
            tile[(c4 + 1) * 68 + row] = (short)f2bf(v.y);
            tile[(c4 + 2) * 68 + row] = (short)f2bf(v.z);
            tile[(c4 + 3) * 68 + row] = (short)f2bf(v.w);
        }
        __syncthreads();
#pragma unroll
        for (int it = 0; it < 4; ++it) {
            const int f4 = tid + it * 256;
            const int d = f4 >> 4, o4 = (f4 & 15) * 4;
            u16x4 w = *(const u16x4*)&tile[d * 68 + o4];
            *(u16x4*)&VTbf[(size_t)d * S + j0 + o4] = w;
        }
    }
}

// ---- main: 4 compute waves + 1 u-producer wave ----
__launch_bounds__(320, 2)
__global__ void fused_main(const short* __restrict__ Qbf,
                           const short* __restrict__ Kbf,
                           const short* __restrict__ VTbf,
                           const float* __restrict__ Ud,
                           const float* __restrict__ RR,
                           float* __restrict__ Opart,            // [NCHUNK][S][D]
                           int* __restrict__ sumr)
{
    __shared__ short kb[2][8 * 512];          // K tile 64x64, fragment-major, dbuf
    __shared__ short vb[2][8 * 512];          // V^T tile 64x64, fragment-major, dbuf
    __shared__ short pb[4 * 16 * LDP];        // per-wave P relayout
    __shared__ unsigned char um8[2][64 * 16]; // keep-nibbles [buf][row*16+byte], dbuf
    __shared__ int red[4];

    const int tid  = threadIdx.x;
    const int w    = tid >> 6;                // 0..3 compute, 4 producer
    const int lane = tid & 63;
    const int quad = lane >> 4;
    const int n16  = lane & 15;

    const int ib  = blockIdx.x & 63;
    const int ic  = blockIdx.x >> 6;          // 0..NCHUNK-1
    const int i0  = ib * 64;
    const int jbase = ic * JCHUNK;

    const bool comp = (w < 4);
    const int i0w = i0 + (comp ? w * 16 : 0);

    // consumer state
    s16x8 aQ[2];
    float rr[4];
    f32x4 accO[4];
    float lsum = 0.f;
    short* pw = pb + (comp ? w : 0) * 16 * LDP;
    const int e0 = w * 2, e1 = w * 2 + 1;
    const unsigned upos = ((unsigned)(n16 >> 2) << 3) | (unsigned)(n16 & 3);

    if (comp) {
#pragma unroll
        for (int ks = 0; ks < 2; ++ks)
            aQ[ks] = *(const s16x8*)&Qbf[(size_t)(i0w + n16) * D + ks * 32 + quad * 8];
#pragma unroll
        for (int rg = 0; rg < 4; ++rg) rr[rg] = RR[i0w + quad * 4 + rg];
#pragma unroll
        for (int ds = 0; ds < 4; ++ds) accO[ds] = (f32x4){0.f, 0.f, 0.f, 0.f};
    }

    // producer state: u rows i0..i0+63; load r covers row r*4+(lane>>4), cols (lane&15)*4
    const float* ub0 = Ud + (size_t)i0 * S;
    float4 up[2][16];           // 2 tiles of u in flight (pinned by clobbers)

    // ---- prologue ----
    if (comp) {
        const int j0 = jbase;
        __builtin_amdgcn_global_load_lds(
            (g_u32*)&Kbf[(size_t)(j0 + (e0 >> 1) * 16 + n16) * D + (e0 & 1) * 32 + quad * 8],
            (lds_u32*)&kb[0][e0 * 512], 16, 0, 0);
        __builtin_amdgcn_global_load_lds(
            (g_u32*)&Kbf[(size_t)(j0 + (e1 >> 1) * 16 + n16) * D + (e1 & 1) * 32 + quad * 8],
            (lds_u32*)&kb[0][e1 * 512], 16, 0, 0);
        __builtin_amdgcn_global_load_lds(
            (g_u32*)&VTbf[(size_t)((e0 & 3) * 16 + n16) * S + j0 + (e0 >> 2) * 32 + quad * 8],
            (lds_u32*)&vb[0][e0 * 512], 16, 0, 0);
        __builtin_amdgcn_global_load_lds(
            (g_u32*)&VTbf[(size_t)((e1 & 3) * 16 + n16) * S + j0 + (e1 >> 2) * 32 + quad * 8],
            (lds_u32*)&vb[0][e1 * 512], 16, 0, 0);
        CLOBBER();
    } else {
#pragma unroll
        for (int r = 0; r < 16; ++r)
            up[0][r] = *(const float4*)&ub0[(size_t)(r * 4 + quad) * S + jbase + n16 * 4];
        CLOBBER();
#pragma unroll
        for (int r = 0; r < 16; ++r)
            up[1][r] = *(const float4*)&ub0[(size_t)(r * 4 + quad) * S + jbase + 64 + n16 * 4];
        CLOBBER();
        // pack u(0) -> um8[0] (auto-waits u(0) only; u(1) stays in flight)
#pragma unroll
        for (int r = 0; r < 16; ++r) {
            const float4 v = up[0][r];
            unsigned nib = (v.x >= 0.1f ? 1u : 0u) | (v.y >= 0.1f ? 2u : 0u)
                         | (v.z >= 0.1f ? 4u : 0u) | (v.w >= 0.1f ? 8u : 0u);
            um8[0][r * 64 + lane] = (unsigned char)nib;   // block row r*4+quad, byte n16
        }
        __asm__ volatile("s_waitcnt lgkmcnt(0)" ::: "memory");
    }

#pragma unroll
    for (int jt = 0; jt < NTILES; ++jt) {
        const int bu = jt & 1;
        const int nb = bu ^ 1;
        const int j0 = jbase + jt * JT;
        const bool last = (jt + 1 == NTILES);

        if (comp) {
            // (a) K/V DMAs for tile t+1 into [nb]; per-wave vmcnt ledger = 4/tile
            if (!last) {
                const int j1 = j0 + JT;
                __builtin_amdgcn_global_load_lds(
                    (g_u32*)&Kbf[(size_t)(j1 + (e0 >> 1) * 16 + n16) * D + (e0 & 1) * 32 + quad * 8],
                    (lds_u32*)&kb[nb][e0 * 512], 16, 0, 0);
                __builtin_amdgcn_global_load_lds(
                    (g_u32*)&Kbf[(size_t)(j1 + (e1 >> 1) * 16 + n16) * D + (e1 & 1) * 32 + quad * 8],
                    (lds_u32*)&kb[nb][e1 * 512], 16, 0, 0);
                __builtin_amdgcn_global_load_lds(
                    (g_u32*)&VTbf[(size_t)((e0 & 3) * 16 + n16) * S + j1 + (e0 >> 2) * 32 + quad * 8],
                    (lds_u32*)&vb[nb][e0 * 512], 16, 0, 0);
                __builtin_amdgcn_global_load_lds(
                    (g_u32*)&VTbf[(size_t)((e1 & 3) * 16 + n16) * S + j1 + (e1 >> 2) * 32 + quad * 8],
                    (lds_u32*)&vb[nb][e1 * 512], 16, 0, 0);
                CLOBBER();
                __asm__ volatile("s_waitcnt vmcnt(4)" ::: "memory");  // drain t's DMAs
            } else {
                __asm__ volatile("s_waitcnt vmcnt(0)" ::: "memory");
            }
        } else {
            // (a') producer: issue u(t+2) into up[bu] (parity: (jt+2)&1 == bu)
            if (jt + 2 < NTILES) {
                const int j2 = jbase + (jt + 2) * JT;
#pragma unroll
                for (int r = 0; r < 16; ++r)
                    up[bu][r] = *(const float4*)&ub0[(size_t)(r * 4 + quad) * S + j2 + n16 * 4];
                CLOBBER();
            }
        }

        __builtin_amdgcn_s_barrier();
        CLOBBER();

        if (comp) {
            // (c) QK^T + epilogue: masks from um8[bu] — THE FIX: + w*16 row offset
            unsigned mar[4][4];
#pragma unroll
            for (int rg = 0; rg < 4; ++rg) {
                const uint4 m4 = *(const uint4*)&um8[bu][(w * 16 + quad * 4 + rg) * 16];
                mar[rg][0] = m4.x; mar[rg][1] = m4.y; mar[rg][2] = m4.z; mar[rg][3] = m4.w;
            }
#pragma unroll
            for (int cs = 0; cs < 4; ++cs) {
                f32x4 acc = (f32x4){0.f, 0.f, 0.f, 0.f};
#pragma unroll
                for (int ks = 0; ks < 2; ++ks) {
                    s16x8 bK = *(const s16x8*)&kb[bu][(cs * 2 + ks) * 512 + lane * 8];
                    acc = __builtin_amdgcn_mfma_f32_16x16x32_bf16(aQ[ks], bK, acc, 0, 0, 0);
                }
#pragma unroll
                for (int rg = 0; rg < 4; ++rg) {
                    const float t = ((mar[rg][cs] >> upos) & 1u) ? acc[rg] : 0.0f;
                    const float r = floorf(t * rr[rg]);
                    lsum += r;
                    pw[(quad * 4 + rg) * LDP + cs * 16 + n16] = (short)f2bf(t * r);
                }
            }
            // (d) within-wave LDS drain for pb
            __builtin_amdgcn_wave_barrier();
            __asm__ volatile("s_waitcnt lgkmcnt(0)" ::: "memory");
            __builtin_amdgcn_wave_barrier();
            // (e) PV
#pragma unroll
            for (int ksj = 0; ksj < 2; ++ksj) {
                s16x8 aP = *(const s16x8*)&pw[n16 * LDP + ksj * 32 + quad * 8];
#pragma unroll
                for (int ds = 0; ds < 4; ++ds) {
                    s16x8 bV = *(const s16x8*)&vb[bu][(ksj * 4 + ds) * 512 + lane * 8];
                    accO[ds] = __builtin_amdgcn_mfma_f32_16x16x32_bf16(aP, bV, accO[ds], 0, 0, 0);
                }
            }
        } else {
            // producer compute-slot: pack u(t+1) from up[nb] -> um8[nb]
            if (!last) {
#pragma unroll
                for (int r = 0; r < 16; ++r) {
                    const float4 v = up[nb][r];
                    unsigned nib = (v.x >= 0.1f ? 1u : 0u) | (v.y >= 0.1f ? 2u : 0u)
                                 | (v.z >= 0.1f ? 4u : 0u) | (v.w >= 0.1f ? 8u : 0u);
                    um8[nb][r * 64 + lane] = (unsigned char)nib;
                }
                __asm__ volatile("s_waitcnt lgkmcnt(0)" ::: "memory");
            }
        }

        // (f) end barrier: masks(t+1) visible; [bu] free for next tile's DMAs
        CLOBBER();
        __builtin_amdgcn_s_barrier();
        CLOBBER();
    }

    // deterministic partial stores (compute waves only)
    if (comp) {
        float* op = Opart + (size_t)ic * S * D;
#pragma unroll
        for (int ds = 0; ds < 4; ++ds) {
            const int d = ds * 16 + n16;
#pragma unroll
            for (int rg = 0; rg < 4; ++rg) {
                const int i = i0w + quad * 4 + rg;
                op[(size_t)i * D + d] = accO[ds][rg];
            }
        }
        for (int off = 32; off; off >>= 1) lsum += __shfl_down(lsum, off);
        if (lane == 0) red[w] = (int)lsum;
    }
    __syncthreads();
    if (tid == 0) atomicAdd(sumr, red[0] + red[1] + red[2] + red[3]);
}

// ---- reduce partials over NCHUNK + apply 1/R ----
__global__ void reduce_out(const float* __restrict__ Opart,
                           const int* __restrict__ sumr,
                           float* __restrict__ out) {
    const int idx = blockIdx.x * 256 + threadIdx.x;   // 65536 float4 groups
    const float invR = 1.0f / (float)(*sumr);         // |R| < 2^24: exact
    float sx = 0.f, sy = 0.f, sz = 0.f, sw = 0.f;
#pragma unroll
    for (int c = 0; c < NCHUNK; ++c) {
        const float4 v = ((const float4*)(Opart + (size_t)c * S * D))[idx];
        sx += v.x; sy += v.y; sz += v.z; sw += v.w;
    }
    float4 o; o.x = sx * invR; o.y = sy * invR; o.z = sz * invR; o.w = sw * invR;
    ((float4*)out)[idx] = o;
}

extern "C" void kernel_launch(void* const* d_in, const int* in_sizes, int n_in,
                              void* d_out, int out_size, void* d_ws, size_t ws_size,
                              hipStream_t stream) {
    (void)in_sizes; (void)n_in; (void)out_size; (void)ws_size;
    const float* Q  = (const float*)d_in[0];
    const float* Kf = (const float*)d_in[1];
    const float* V  = (const float*)d_in[2];
    const float* Ud = (const float*)d_in[3];
    const float* RR = (const float*)d_in[4];
    float* out = (float*)d_out;

    // ws layout: Opart 8MB | Qbf 512KB | Kbf 512KB | VTbf 512KB | sumr
    char* ws = (char*)d_ws;
    float* Opart = (float*)ws;                                  // 8 MB
    short* Qbf  = (short*)(ws + (8u << 20));
    short* Kbf  = (short*)(ws + (8u << 20) + (512u << 10));
    short* VTbf = (short*)(ws + (8u << 20) + (1024u << 10));
    int*   sumr = (int*)  (ws + (8u << 20) + (1536u << 10));

    prep_all<<<dim3(576), dim3(256), 0, stream>>>(Q, Kf, V, Qbf, Kbf, VTbf, sumr);
    fused_main<<<dim3(64 * NCHUNK), dim3(320), 0, stream>>>(
        Qbf, Kbf, VTbf, Ud, RR, Opart, sumr);
    reduce_out<<<dim3(256), dim3(256), 0, stream>>>(Opart, sumr, out);
}